// Round 12
// baseline (120.932 us; speedup 1.0000x reference)
//
#include <hip/hip_runtime.h>

// Problem constants
#define NB    2048   // n_back (k)
#define NB4   512    // NB/4 in f32x4 units
#define NOUT  2048   // H*W*COUT
#define NDIM  2048   // H*W*CIN

// Output flat offsets (floats) in d_out: [w_u_, b_u_, w_l_, b_l_]
#define OFF_BU  16777216ull
#define OFF_WL  16785408ull
#define OFF_BL  33562624ull

// ws layout (floats): [0,16384) bias partials (2,4,2048); [16384,16960) T
#define WS_T    16384

typedef float f32x4 __attribute__((ext_vector_type(4)));

// T[co*72 + ci*9 + kh*3 + kw] = kern[((kh*3+kw)*8+ci)*8+co]
// -> per co, 72 CONTIGUOUS floats: uniform-address loads become wide
// s_load batches into the scalar register file (round-10 mechanism).
__global__ void prep_kernel(const float* __restrict__ kern, float* __restrict__ T) {
    const int i = blockIdx.x * 64 + threadIdx.x;   // 0..575
    if (i < 576) {
        const int kw = i % 3, kh = (i / 3) % 3, ci = (i / 9) % 8, co = i / 72;
        T[i] = kern[((kh * 3 + kw) * 8 + ci) * 8 + co];
    }
}

// co-outer conv-backward, f32x4 lanes, 2 owned rows/thread,
// BATCHED loads: all 12 f32x4 input loads of a co-iteration are issued
// up front (u[4][3], 48 VGPR) before the 288-FMA block consumes them.
// Round-11 was latency-bound (VALUBusy 33%, HBM 9%): 3 loads per s-step
// consumed immediately -> ~13% duty per wave. Batching 12 loads gives
// ~576 cycles of FMA to cover one LLC round trip.
// VGPR budget: acc 64 + u 48 + addr ~12 < 128 -> 4 waves/SIMD held.
__global__ __launch_bounds__(256, 4) void conv_back_kernel(
    const float* __restrict__ wu,
    const float* __restrict__ wl,
    const float* __restrict__ Tw,     // (8co, 72) transposed weights
    const float* __restrict__ bias,   // (8)
    float* __restrict__ outbuf,       // full d_out base
    float* __restrict__ bias_ws)      // (2,4,2048) partial bias sums
{
    const int bid = blockIdx.x;            // 0..2047
    const int klo = bid & 7;               // XCD id = k-chunk (k-disjoint)
    const int j   = bid >> 3;              // per-XCD order
    const int wig = j & 3;                 // wi group
    const int hr  = (j >> 2) & 7;          // 2-row group
    const int sl  = j >> 5;                // 0..7 (t,b)
    const int t = sl >> 2, b = sl & 3;
    const int kl  = threadIdx.x & 63;
    const int sub = threadIdx.x >> 6;      // 0..3
    const int wi  = wig * 4 + sub;         // 0..15, wave-uniform
    const int r0  = hr * 2;                // first owned out row
    const int k4  = klo * 64 + kl;         // f32x4 index over k, 0..511

    const f32x4* __restrict__ in =
        (const f32x4*)(t ? wl : wu) + (size_t)b * NOUT * NB4 + k4;
    f32x4* __restrict__ wout =
        (f32x4*)(outbuf + (t ? OFF_WL : 0)) + (size_t)b * NDIM * NB4 + k4;

    const bool vlo = wi > 0;               // wave-uniform edge masks
    const bool vhi = wi < 15;

    f32x4 acc[2][8];
    #pragma unroll
    for (int m = 0; m < 2; ++m)
        #pragma unroll
        for (int ci = 0; ci < 8; ++ci) acc[m][ci] = (f32x4)(0.f);
    f32x4 pb = (f32x4)(0.f);

    #pragma unroll 1
    for (int co = 0; co < 8; ++co) {
        const float* __restrict__ tb = Tw + co * 72;  // uniform -> s_loads
        const float bco = bias[co];

        // ---- batched load phase: 12 independent loads in flight ----
        f32x4 u[4][3];                      // [s][wi-1, wi, wi+1]
        #pragma unroll
        for (int s = 0; s < 4; ++s) {
            const int ho = r0 - 1 + s;
            if ((unsigned)ho < 16u) {       // block-uniform (hr edges only)
                const size_t base = (size_t)((ho * 16 + wi) * 8 + co) * NB4;
                u[s][0] = vlo ? in[base - 8 * NB4] : (f32x4)(0.f);
                u[s][1] =       in[base];
                u[s][2] = vhi ? in[base + 8 * NB4] : (f32x4)(0.f);
            } else {
                u[s][0] = (f32x4)(0.f);
                u[s][1] = (f32x4)(0.f);
                u[s][2] = (f32x4)(0.f);
            }
        }

        // owned rows are s=1 (r0) and s=2 (r0+1)
        pb += bco * (u[1][1] + u[2][1]);

        // ---- FMA phase: 288 f32x4 FMAs consuming the batch ----
        #pragma unroll
        for (int s = 0; s < 4; ++s)
            #pragma unroll
            for (int kh = 0; kh < 3; ++kh) {
                const int m = s - 2 + kh;           // target owned row
                if (m >= 0 && m <= 1) {             // compile-time filter
                    #pragma unroll
                    for (int ci = 0; ci < 8; ++ci)
                        #pragma unroll
                        for (int kw = 0; kw < 3; ++kw) {
                            const float Kv = tb[ci * 9 + kh * 3 + kw]; // SGPR
                            acc[m][ci] += Kv * u[s][2 - kw];   // dw = 1-kw
                        }
                }
            }
    }

    #pragma unroll
    for (int m = 0; m < 2; ++m)
        #pragma unroll
        for (int ci = 0; ci < 8; ++ci)
            wout[(size_t)(((r0 + m) * 16 + wi) * 8 + ci) * NB4] = acc[m][ci];

    // reduce bias partials across the 4 sub-waves (same k4, different wi)
    __shared__ f32x4 red[4][64];
    red[sub][kl] = pb;
    __syncthreads();
    if (sub == 0) {
        f32x4 tot = red[0][kl] + red[1][kl] + red[2][kl] + red[3][kl];
        float* bws = bias_ws + t * 8192 + b * 2048 + 4 * k4;
        atomicAdd(bws + 0, tot.x);
        atomicAdd(bws + 1, tot.y);
        atomicAdd(bws + 2, tot.z);
        atomicAdd(bws + 3, tot.w);
    }
}

// b_out_ = b_in + ws ; 16384 outputs (2 ul * 4 b * 2048 k)
__global__ void bias_finalize(const float* __restrict__ bu,
                              const float* __restrict__ bl,
                              const float* __restrict__ ws,
                              float* __restrict__ out)
{
    const int idx = blockIdx.x * blockDim.x + threadIdx.x;   // 0..16383
    const int ul  = idx >> 13;
    const int r   = idx & 8191;                              // b*2048 + k
    const float* bin = ul ? bl : bu;
    const size_t off = ul ? OFF_BL : OFF_BU;
    out[off + r] = bin[r] + ws[(size_t)ul * 8192 + r];
}

extern "C" void kernel_launch(void* const* d_in, const int* in_sizes, int n_in,
                              void* d_out, int out_size, void* d_ws, size_t ws_size,
                              hipStream_t stream) {
    // inputs: 0=x (unused), 1=kernel, 2=bias, 3=w_out_u, 4=b_out_u, 5=w_out_l, 6=b_out_l
    const float* kern = (const float*)d_in[1];
    const float* bias = (const float*)d_in[2];
    const float* wu   = (const float*)d_in[3];
    const float* bu   = (const float*)d_in[4];
    const float* wl   = (const float*)d_in[5];
    const float* bl   = (const float*)d_in[6];
    float* out = (float*)d_out;
    float* ws  = (float*)d_ws;

    // zero the 64 KB bias-partial region (graph replays re-run this node)
    (void)hipMemsetAsync(ws, 0, 2ull * 4 * NB * sizeof(float), stream);

    prep_kernel<<<9, 64, 0, stream>>>(kern, ws + WS_T);
    conv_back_kernel<<<dim3(2048), dim3(256), 0, stream>>>(wu, wl, ws + WS_T, bias, out, ws);
    bias_finalize<<<64, 256, 0, stream>>>(bu, bl, ws, out);
}

// Round 13
// 86.991 us; speedup vs baseline: 1.3902x; 1.3902x over previous
//
#include <hip/hip_runtime.h>

// Problem constants
#define NB    2048   // n_back (k)
#define NB4   512    // NB/4 in f32x4 units
#define NOUT  2048   // H*W*COUT
#define NDIM  2048   // H*W*CIN

// Output flat offsets (floats) in d_out: [w_u_, b_u_, w_l_, b_l_]
#define OFF_BU  16777216ull
#define OFF_WL  16785408ull
#define OFF_BL  33562624ull

// ws layout (floats): [0,16384) bias partials (2,4,2048); [16384,16960) T
#define WS_T    16384

typedef float f32x4 __attribute__((ext_vector_type(4)));

// T[co*72 + ci*9 + kh*3 + kw] = kern[((kh*3+kw)*8+ci)*8+co]
// -> per co, 72 CONTIGUOUS floats: uniform-address loads become wide
// s_load batches into the scalar register file (round-10 mechanism).
__global__ void prep_kernel(const float* __restrict__ kern, float* __restrict__ T) {
    const int i = blockIdx.x * 64 + threadIdx.x;   // 0..575
    if (i < 576) {
        const int kw = i % 3, kh = (i / 3) % 3, ci = (i / 9) % 8, co = i / 72;
        T[i] = kern[((kh * 3 + kw) * 8 + ci) * 8 + co];
    }
}

// co-outer conv-backward, f32x4 lanes, 2 owned rows/thread, batched loads.
// ROUND-12 LESSON: under __launch_bounds__(256,4) the backend pinned VGPR
// at 64 and spilled the u[4][3] batch to scratch (+100MB writes). Same
// code, launch_bounds (256,2): VGPR cap 256 -> the 12-load batch stays in
// registers. Occupancy 4->~3 waves/SIMD but per-wave loads-in-flight 3->12:
// net ~3x MLP, which is what the ~500cy LLC latency needs covered.
__global__ __launch_bounds__(256, 2) void conv_back_kernel(
    const float* __restrict__ wu,
    const float* __restrict__ wl,
    const float* __restrict__ Tw,     // (8co, 72) transposed weights
    const float* __restrict__ bias,   // (8)
    float* __restrict__ outbuf,       // full d_out base
    float* __restrict__ bias_ws)      // (2,4,2048) partial bias sums
{
    const int bid = blockIdx.x;            // 0..2047
    const int klo = bid & 7;               // XCD id = k-chunk (k-disjoint)
    const int j   = bid >> 3;              // per-XCD order
    const int wig = j & 3;                 // wi group
    const int hr  = (j >> 2) & 7;          // 2-row group
    const int sl  = j >> 5;                // 0..7 (t,b)
    const int t = sl >> 2, b = sl & 3;
    const int kl  = threadIdx.x & 63;
    const int sub = threadIdx.x >> 6;      // 0..3
    const int wi  = wig * 4 + sub;         // 0..15, wave-uniform
    const int r0  = hr * 2;                // first owned out row
    const int k4  = klo * 64 + kl;         // f32x4 index over k, 0..511

    const f32x4* __restrict__ in =
        (const f32x4*)(t ? wl : wu) + (size_t)b * NOUT * NB4 + k4;
    f32x4* __restrict__ wout =
        (f32x4*)(outbuf + (t ? OFF_WL : 0)) + (size_t)b * NDIM * NB4 + k4;

    const bool vlo = wi > 0;               // wave-uniform edge masks
    const bool vhi = wi < 15;

    f32x4 acc[2][8];
    #pragma unroll
    for (int m = 0; m < 2; ++m)
        #pragma unroll
        for (int ci = 0; ci < 8; ++ci) acc[m][ci] = (f32x4)(0.f);
    f32x4 pb = (f32x4)(0.f);

    #pragma unroll 1
    for (int co = 0; co < 8; ++co) {
        const float* __restrict__ tb = Tw + co * 72;  // uniform -> s_loads
        const float bco = bias[co];

        // ---- batched load phase: 12 independent loads in flight ----
        f32x4 u[4][3];                      // [s][wi-1, wi, wi+1]
        #pragma unroll
        for (int s = 0; s < 4; ++s) {
            const int ho = r0 - 1 + s;
            if ((unsigned)ho < 16u) {       // block-uniform (hr edges only)
                const size_t base = (size_t)((ho * 16 + wi) * 8 + co) * NB4;
                u[s][0] = vlo ? in[base - 8 * NB4] : (f32x4)(0.f);
                u[s][1] =       in[base];
                u[s][2] = vhi ? in[base + 8 * NB4] : (f32x4)(0.f);
            } else {
                u[s][0] = (f32x4)(0.f);
                u[s][1] = (f32x4)(0.f);
                u[s][2] = (f32x4)(0.f);
            }
        }

        // owned rows are s=1 (r0) and s=2 (r0+1)
        pb += bco * (u[1][1] + u[2][1]);

        // ---- FMA phase: 288 f32x4 FMAs consuming the batch ----
        #pragma unroll
        for (int s = 0; s < 4; ++s)
            #pragma unroll
            for (int kh = 0; kh < 3; ++kh) {
                const int m = s - 2 + kh;           // target owned row
                if (m >= 0 && m <= 1) {             // compile-time filter
                    #pragma unroll
                    for (int ci = 0; ci < 8; ++ci)
                        #pragma unroll
                        for (int kw = 0; kw < 3; ++kw) {
                            const float Kv = tb[ci * 9 + kh * 3 + kw]; // SGPR
                            acc[m][ci] += Kv * u[s][2 - kw];   // dw = 1-kw
                        }
                }
            }
    }

    #pragma unroll
    for (int m = 0; m < 2; ++m)
        #pragma unroll
        for (int ci = 0; ci < 8; ++ci)
            wout[(size_t)(((r0 + m) * 16 + wi) * 8 + ci) * NB4] = acc[m][ci];

    // reduce bias partials across the 4 sub-waves (same k4, different wi)
    __shared__ f32x4 red[4][64];
    red[sub][kl] = pb;
    __syncthreads();
    if (sub == 0) {
        f32x4 tot = red[0][kl] + red[1][kl] + red[2][kl] + red[3][kl];
        float* bws = bias_ws + t * 8192 + b * 2048 + 4 * k4;
        atomicAdd(bws + 0, tot.x);
        atomicAdd(bws + 1, tot.y);
        atomicAdd(bws + 2, tot.z);
        atomicAdd(bws + 3, tot.w);
    }
}

// b_out_ = b_in + ws ; 16384 outputs (2 ul * 4 b * 2048 k)
__global__ void bias_finalize(const float* __restrict__ bu,
                              const float* __restrict__ bl,
                              const float* __restrict__ ws,
                              float* __restrict__ out)
{
    const int idx = blockIdx.x * blockDim.x + threadIdx.x;   // 0..16383
    const int ul  = idx >> 13;
    const int r   = idx & 8191;                              // b*2048 + k
    const float* bin = ul ? bl : bu;
    const size_t off = ul ? OFF_BL : OFF_BU;
    out[off + r] = bin[r] + ws[(size_t)ul * 8192 + r];
}

extern "C" void kernel_launch(void* const* d_in, const int* in_sizes, int n_in,
                              void* d_out, int out_size, void* d_ws, size_t ws_size,
                              hipStream_t stream) {
    // inputs: 0=x (unused), 1=kernel, 2=bias, 3=w_out_u, 4=b_out_u, 5=w_out_l, 6=b_out_l
    const float* kern = (const float*)d_in[1];
    const float* bias = (const float*)d_in[2];
    const float* wu   = (const float*)d_in[3];
    const float* bu   = (const float*)d_in[4];
    const float* wl   = (const float*)d_in[5];
    const float* bl   = (const float*)d_in[6];
    float* out = (float*)d_out;
    float* ws  = (float*)d_ws;

    // zero the 64 KB bias-partial region (graph replays re-run this node)
    (void)hipMemsetAsync(ws, 0, 2ull * 4 * NB * sizeof(float), stream);

    prep_kernel<<<9, 64, 0, stream>>>(kern, ws + WS_T);
    conv_back_kernel<<<dim3(2048), dim3(256), 0, stream>>>(wu, wl, ws + WS_T, bias, out, ws);
    bias_finalize<<<64, 256, 0, stream>>>(bu, bl, ws, out);
}